// Round 11
// baseline (172.729 us; speedup 1.0000x reference)
//
#include <hip/hip_runtime.h>
#include <hip/hip_fp16.h>

typedef _Float16 f16;
typedef _Float16 v2hf __attribute__((ext_vector_type(2)));
typedef _Float16 v8hf __attribute__((ext_vector_type(8)));
typedef __fp16 v2fp __attribute__((ext_vector_type(2)));
typedef float v4f __attribute__((ext_vector_type(4)));
typedef float v16f __attribute__((ext_vector_type(16)));
typedef unsigned int v4u __attribute__((ext_vector_type(4)));

#define NROW 9216
#define SZH ((size_t)NROW * 768)

__device__ __forceinline__ float softplus_f(float a) {
  return fmaxf(a, 0.f) + log1pf(__expf(-fabsf(a)));
}

__device__ __forceinline__ unsigned int packh(float a, float b) {
  union { v2fp h; unsigned int u; } z;
  z.h = __builtin_amdgcn_cvt_pkrtz(a, b);
  return z.u;
}

// async global->LDS, 16B per lane. LDS dest must be wave-uniform base; HW
// writes base + lane*16. Global addr is per-lane (pre-swizzled source).
__device__ __forceinline__ void gload16(const void* g, void* l) {
  __builtin_amdgcn_global_load_lds(
      (const __attribute__((address_space(1))) unsigned int*)(unsigned long long)g,
      (__attribute__((address_space(3))) unsigned int*)(unsigned int)(unsigned long long)l,
      16, 0, 0);
}

// ------------------------------------------------------------------
// prep: LayerNorm->f16 xn | W transpose->f16 | softplus rates + bias concat
// rates are pre-scaled by log2(e) so staging uses exp2f (one fewer v_mul/exp)
// ------------------------------------------------------------------
__global__ __launch_bounds__(256) void prep_kernel(
    const float* __restrict__ x, const float* __restrict__ lg, const float* __restrict__ lb,
    const float* __restrict__ Wq, const float* __restrict__ Wk, const float* __restrict__ Wv,
    const float* __restrict__ Wo, const float* __restrict__ ak, const float* __restrict__ av,
    const float* __restrict__ bq, const float* __restrict__ bk, const float* __restrict__ bv,
    f16* __restrict__ xn, f16* __restrict__ wt, float* __restrict__ biasqkv,
    float* __restrict__ rates)
{
  __shared__ float tile[64][65];
  __shared__ float red[8];
  int bid = blockIdx.x, tid = threadIdx.x;
  if (bid < NROW) {
    const float* xr = x + (size_t)bid * 768;
    float v0 = xr[tid], v1 = xr[tid + 256], v2 = xr[tid + 512];
    float s1 = v0 + v1 + v2;
    float s2 = v0 * v0 + v1 * v1 + v2 * v2;
    #pragma unroll
    for (int off = 32; off >= 1; off >>= 1) {
      s1 += __shfl_xor(s1, off);
      s2 += __shfl_xor(s2, off);
    }
    int w = tid >> 6;
    if ((tid & 63) == 0) { red[w] = s1; red[4 + w] = s2; }
    __syncthreads();
    s1 = red[0] + red[1] + red[2] + red[3];
    s2 = red[4] + red[5] + red[6] + red[7];
    float mu = s1 * (1.f / 768.f);
    float var = s2 * (1.f / 768.f) - mu * mu;
    float rs = rsqrtf(var + 1e-5f);
    f16* xo = xn + (size_t)bid * 768;
    xo[tid]       = (f16)((v0 - mu) * rs * lg[tid] + lb[tid]);
    xo[tid + 256] = (f16)((v1 - mu) * rs * lg[tid + 256] + lb[tid + 256]);
    xo[tid + 512] = (f16)((v2 - mu) * rs * lg[tid + 512] + lb[tid + 512]);
    return;
  }
  bid -= NROW;
  if (bid < 576) {
    int wsel = bid / 144, t2 = bid % 144, tr = t2 / 12, tc = t2 % 12;
    const float* W = (wsel == 0) ? Wq : ((wsel == 1) ? Wk : ((wsel == 2) ? Wv : Wo));
    f16* WT = wt + (size_t)wsel * 589824;
    int r = tid >> 2, c0 = (tid & 3) * 16;
    #pragma unroll
    for (int j = 0; j < 16; j++)
      tile[r][c0 + j] = W[(size_t)(tr * 64 + r) * 768 + tc * 64 + c0 + j];
    __syncthreads();
    #pragma unroll
    for (int j = 0; j < 16; j++)
      WT[(size_t)(tc * 64 + r) * 768 + tr * 64 + c0 + j] = (f16)tile[c0 + j][r];
    return;
  }
  // rates pre-scaled by log2(e): exp(-r*d) == exp2f(-(r*log2e)*d)
  if (tid < 64) rates[tid] = softplus_f(ak[tid]) * 1.44269504f;
  else if (tid < 128) rates[tid] = softplus_f(av[tid - 64]) * 1.44269504f;
  for (int i = tid; i < 2304; i += 256)
    biasqkv[i] = (i < 768) ? bq[i] : ((i < 1536) ? bk[i - 768] : bv[i - 1536]);
}

// ------------------------------------------------------------------
// GEMM (R5/R10-proven, byte-identical): A[M,768] x WT[N,768] + bias[N]
// 128x128 tile, 256 thr, K-step 64, double-buffered global_load_lds(16B)
// with counted vmcnt(8); two raw s_barriers per K-step.
// XCD-chunked block swizzle (nwg % 8 == 0 for both grids).
// ------------------------------------------------------------------
__global__ __launch_bounds__(256) void gemm_kernel(
    const f16* __restrict__ A, const f16* __restrict__ WT,
    const float* __restrict__ bias,
    f16* __restrict__ outh, float* __restrict__ outf, int f32out)
{
  __shared__ __align__(16) f16 At[2][128 * 64];
  __shared__ __align__(16) f16 Bt[2][128 * 64];
  int bid0 = blockIdx.y * gridDim.x + blockIdx.x;
  int nwg = gridDim.x * gridDim.y;
  int nid = (bid0 & 7) * (nwg >> 3) + (bid0 >> 3);
  int cols = gridDim.y;
  int mb = nid / cols, nb = nid % cols;
  int tid = threadIdx.x, lane = tid & 63, w = tid >> 6;
  int wr = w >> 1, wc = w & 1;
  v4f acc[4][4];
  #pragma unroll
  for (int i = 0; i < 4; i++)
    #pragma unroll
    for (int j = 0; j < 4; j++) acc[i][j] = (v4f){0.f, 0.f, 0.f, 0.f};
  int arow0 = mb * 128, brow0 = nb * 128;
  int rb = w * 32 + (lane >> 3);
  int ch = lane & 7;
  auto stage = [&](int buf, int k0) {
    #pragma unroll
    for (int j = 0; j < 4; j++) {
      int row = rb + j * 8;
      int sc = ((ch ^ (row & 7)) << 3);
      gload16(A  + (size_t)(arow0 + row) * 768 + k0 + sc, (char*)At[buf] + w * 4096 + j * 1024);
      gload16(WT + (size_t)(brow0 + row) * 768 + k0 + sc, (char*)Bt[buf] + w * 4096 + j * 1024);
    }
  };
  stage(0, 0);
  for (int ks = 0; ks < 12; ++ks) {
    int cur = ks & 1;
    if (ks < 11) {
      stage(cur ^ 1, (ks + 1) * 64);
      asm volatile("s_waitcnt vmcnt(8)" ::: "memory");   // current tile landed
    } else {
      asm volatile("s_waitcnt vmcnt(0)" ::: "memory");
    }
    __builtin_amdgcn_s_barrier();
    __builtin_amdgcn_sched_barrier(0);
    v8hf bf[4][2];
    #pragma unroll
    for (int cf = 0; cf < 4; cf++)
      #pragma unroll
      for (int kk = 0; kk < 2; kk++) {
        int row = wc * 64 + cf * 16 + (lane & 15);
        int bc = kk * 64 + ((lane >> 4) << 4);
        bf[cf][kk] = *(const v8hf*)((char*)Bt[cur] + row * 128 + (bc ^ ((row & 7) << 4)));
      }
    #pragma unroll
    for (int rf = 0; rf < 4; rf++) {
      v8hf af[2];
      int row = wr * 64 + rf * 16 + (lane & 15);
      #pragma unroll
      for (int kk = 0; kk < 2; kk++) {
        int bc = kk * 64 + ((lane >> 4) << 4);
        af[kk] = *(const v8hf*)((char*)At[cur] + row * 128 + (bc ^ ((row & 7) << 4)));
      }
      #pragma unroll
      for (int cf = 0; cf < 4; cf++) {
        acc[rf][cf] = __builtin_amdgcn_mfma_f32_16x16x32_f16(af[0], bf[cf][0], acc[rf][cf], 0, 0, 0);
        acc[rf][cf] = __builtin_amdgcn_mfma_f32_16x16x32_f16(af[1], bf[cf][1], acc[rf][cf], 0, 0, 0);
      }
    }
    __builtin_amdgcn_sched_barrier(0);
    __builtin_amdgcn_s_barrier();
  }
  #pragma unroll
  for (int cf = 0; cf < 4; cf++) {
    int col = nb * 128 + wc * 64 + cf * 16 + (lane & 15);
    float bb = bias[col];
    int z = col / 768;
    int colz = col - z * 768;
    #pragma unroll
    for (int rf = 0; rf < 4; rf++) {
      int row0 = mb * 128 + wr * 64 + rf * 16 + ((lane >> 4) << 2);
      #pragma unroll
      for (int r = 0; r < 4; r++) {
        float val = acc[rf][cf][r] + bb;
        if (f32out) outf[(size_t)(row0 + r) * 768 + col] = val;
        else outh[(size_t)z * SZH + (size_t)(row0 + r) * 768 + colz] = (f16)val;
      }
    }
  }
}

// ------------------------------------------------------------------
// vt: per-head transpose vw [g][576][64] -> vt [g][64][576]
// ------------------------------------------------------------------
__global__ __launch_bounds__(256) void vt_kernel(const f16* __restrict__ vw, f16* __restrict__ vt)
{
  __shared__ f16 tile[64][72];
  int g = blockIdx.x, tc = blockIdx.y;
  int tid = threadIdx.x;
  int tr = tid >> 2, c16 = (tid & 3) * 16;
  const f16* src = vw + (size_t)g * 36864 + (size_t)(tc * 64 + tr) * 64 + c16;
  *(v8hf*)&tile[tr][c16] = *(const v8hf*)src;
  *(v8hf*)&tile[tr][c16 + 8] = *(const v8hf*)(src + 8);
  __syncthreads();
  int d = tid >> 2, t16 = (tid & 3) * 16;
  f16 outv[16];
  #pragma unroll
  for (int j = 0; j < 16; j++) outv[j] = tile[t16 + j][d];
  f16* dst = vt + (size_t)g * 36864 + (size_t)d * 576 + tc * 64 + t16;
  *(v8hf*)dst = *(v8hf*)outv;
  *(v8hf*)(dst + 8) = *(v8hf*)(outv + 8);
}

// ------------------------------------------------------------------
// Attention: block = (gc in [0,576) XCD-swizzled, slice). 6 waves x 32 q.
// Swapped QK^T (S^T via mfma_32x32x16), in-register softmax + P exchange,
// defer-max (T13, THR=8), T5 setprio on MFMA clusters (m191 precedent).
// nslice==3: f16 normalized partials + (m,l).
// ------------------------------------------------------------------
__global__ __launch_bounds__(384, 3) void attn_kernel(
    const f16* __restrict__ qw, const f16* __restrict__ kw, const f16* __restrict__ vt,
    const float* __restrict__ dist, const float* __restrict__ rates,
    f16* __restrict__ aw, f16* __restrict__ parth, float* __restrict__ ml, int nslice)
{
  __shared__ __align__(16) f16 Ke[64 * 64];
  __shared__ __align__(16) f16 Vt[64 * 64];
  __shared__ float dl[576];
  __shared__ float rkv[128];
  int gc = (blockIdx.x & 7) * 72 + (blockIdx.x >> 3);  // bijective (576 = 8*72)
  int sl = blockIdx.y;
  int g = gc / 3, c = gc - g * 3;
  int tid = threadIdx.x, lane = tid & 63, w = tid >> 6;
  int l31 = lane & 31, h = lane >> 5;
  int ntile = 9 / nslice;
  size_t hbase = (size_t)g * 36864;
  if (tid < 128) rkv[tid] = rates[tid];
  for (int t = tid; t < ntile * 64; t += 384)
    dl[t] = dist[(size_t)gc * 576 + sl * ntile * 64 + t];
  __syncthreads();
  v8hf qf[4];
  {
    const f16* qp = qw + hbase + (size_t)(c * 192 + w * 32 + l31) * 64 + h * 8;
    #pragma unroll
    for (int kk = 0; kk < 4; kk++) {
      v8hf v = *(const v8hf*)(qp + kk * 16);
      #pragma unroll
      for (int j = 0; j < 8; j++) v[j] = v[j] * (f16)0.125f;
      qf[kk] = v;
    }
  }
  v16f o0, o1;
  #pragma unroll
  for (int i = 0; i < 16; i++) { o0[i] = 0.f; o1[i] = 0.f; }
  float mrun = -1e30f, lrun = 0.f;
  for (int t = 0; t < ntile; ++t) {
    int mbase = sl * ntile * 64 + t * 64;
    int mloc = t * 64;
    for (int u = tid; u < 1024; u += 384) {
      if (u < 512) {
        int mm = u >> 3, d8 = (u & 7) * 8;
        float dv = dl[mloc + mm];
        v8hf kv = *(const v8hf*)(kw + hbase + (size_t)(mbase + mm) * 64 + d8);
        #pragma unroll
        for (int j = 0; j < 8; j++)
          kv[j] = (f16)((float)kv[j] + exp2f(-rkv[d8 + j] * dv));   // rates pre-scaled by log2e
        *(v8hf*)((char*)Ke + mm * 128 + ((d8 * 2) ^ ((mm & 7) << 4))) = kv;
      } else {
        int uu = u - 512;
        int dd = uu >> 3, m8 = (uu & 7) * 8;
        float rv = rkv[64 + dd];
        v8hf vv = *(const v8hf*)(vt + hbase + (size_t)dd * 576 + mbase + m8);
        #pragma unroll
        for (int j = 0; j < 8; j++)
          vv[j] = (f16)((float)vv[j] + exp2f(-rv * dl[mloc + m8 + j]));
        *(v8hf*)((char*)Vt + dd * 128 + ((m8 * 2) ^ ((dd & 7) << 4))) = vv;
      }
    }
    __syncthreads();
    v16f s0, s1;
    #pragma unroll
    for (int i = 0; i < 16; i++) { s0[i] = 0.f; s1[i] = 0.f; }
    __builtin_amdgcn_s_setprio(1);
    #pragma unroll
    for (int kk = 0; kk < 4; kk++) {
      int bc = kk * 32 + h * 16;
      int sw0 = (l31 & 7) << 4;
      v8hf a0 = *(const v8hf*)((char*)Ke + l31 * 128 + (bc ^ sw0));
      v8hf a1 = *(const v8hf*)((char*)Ke + (32 + l31) * 128 + (bc ^ sw0));
      s0 = __builtin_amdgcn_mfma_f32_32x32x16_f16(a0, qf[kk], s0, 0, 0, 0);
      s1 = __builtin_amdgcn_mfma_f32_32x32x16_f16(a1, qf[kk], s1, 0, 0, 0);
    }
    __builtin_amdgcn_s_setprio(0);
    float tmax = s0[0];
    #pragma unroll
    for (int i = 1; i < 16; i++) tmax = fmaxf(tmax, s0[i]);
    #pragma unroll
    for (int i = 0; i < 16; i++) tmax = fmaxf(tmax, s1[i]);
    tmax = fmaxf(tmax, __shfl_xor(tmax, 32));
    // T13 defer-max: skip O-rescale when per-tile growth <= 8 (P <= e^8, f16-safe)
    if (!__all(tmax - mrun <= 8.f)) {
      float mnew = fmaxf(mrun, tmax);
      float alpha = __expf(mrun - mnew);
      lrun *= alpha;
      #pragma unroll
      for (int i = 0; i < 16; i++) { o0[i] *= alpha; o1[i] *= alpha; }
      mrun = mnew;
    }
    float rs = 0.f;
    #pragma unroll
    for (int i = 0; i < 16; i++) { float p = __expf(s0[i] - mrun); s0[i] = p; rs += p; }
    #pragma unroll
    for (int i = 0; i < 16; i++) { float p = __expf(s1[i] - mrun); s1[i] = p; rs += p; }
    rs += __shfl_xor(rs, 32);
    lrun += rs;
    unsigned int Wd[16], Xd[16];
    #pragma unroll
    for (int i = 0; i < 8; i++) {
      Wd[i]     = packh(s0[2 * i], s0[2 * i + 1]);
      Wd[8 + i] = packh(s1[2 * i], s1[2 * i + 1]);
    }
    #pragma unroll
    for (int i = 0; i < 16; i++) Xd[i] = __shfl_xor((int)Wd[i], 32);
    v4u fw[4];
    fw[0] = h ? (v4u){Xd[2],  Xd[3],  Wd[2],  Wd[3]}  : (v4u){Wd[0],  Wd[1],  Xd[0],  Xd[1]};
    fw[1] = h ? (v4u){Xd[6],  Xd[7],  Wd[6],  Wd[7]}  : (v4u){Wd[4],  Wd[5],  Xd[4],  Xd[5]};
    fw[2] = h ? (v4u){Xd[10], Xd[11], Wd[10], Wd[11]} : (v4u){Wd[8],  Wd[9],  Xd[8],  Xd[9]};
    fw[3] = h ? (v4u){Xd[14], Xd[15], Wd[14], Wd[15]} : (v4u){Wd[12], Wd[13], Xd[12], Xd[13]};
    __builtin_amdgcn_s_setprio(1);
    #pragma unroll
    for (int kk = 0; kk < 4; kk++) {
      int bc = kk * 32 + h * 16;
      int sw0 = (l31 & 7) << 4;
      v8hf a0 = *(const v8hf*)((char*)Vt + l31 * 128 + (bc ^ sw0));
      v8hf a1 = *(const v8hf*)((char*)Vt + (32 + l31) * 128 + (bc ^ sw0));
      union { v4u u; v8hf hh; } pb;
      pb.u = fw[kk];
      o0 = __builtin_amdgcn_mfma_f32_32x32x16_f16(a0, pb.hh, o0, 0, 0, 0);
      o1 = __builtin_amdgcn_mfma_f32_32x32x16_f16(a1, pb.hh, o1, 0, 0, 0);
    }
    __builtin_amdgcn_s_setprio(0);
    __syncthreads();
  }
  float inv = 1.f / lrun;
  if (nslice == 1) {
    f16* ap = aw + hbase + (size_t)(c * 192 + w * 32 + l31) * 64;
    #pragma unroll
    for (int r = 0; r < 16; r++) {
      int d = (r & 3) + 8 * (r >> 2) + 4 * h;
      ap[d]      = (f16)(o0[r] * inv);
      ap[d + 32] = (f16)(o1[r] * inv);
    }
  } else {
    // normalized f16 partials (|O/l| <= max|V_eff|): halves split-K traffic
    f16* pp = parth + ((size_t)sl * 576 + gc) * 12288;
    int q = w * 32 + l31;
    #pragma unroll
    for (int r = 0; r < 16; r++) {
      int d = (r & 3) + 8 * (r >> 2) + 4 * h;
      pp[d * 192 + q]        = (f16)(o0[r] * inv);
      pp[(d + 32) * 192 + q] = (f16)(o1[r] * inv);
    }
    if (h == 0) {
      float* mlp = ml + ((size_t)sl * 576 + gc) * 384;
      mlp[q]       = mrun;
      mlp[192 + q] = lrun;
    }
  }
}

// ------------------------------------------------------------------
// combine split-K normalized partials -> aw f16
// O = sum_s (l_s e^{m_s-M} / L) * O_s_norm,  L = sum_s l_s e^{m_s-M}
// ------------------------------------------------------------------
__global__ __launch_bounds__(192) void comb_kernel(
    const f16* __restrict__ parth, const float* __restrict__ ml, f16* __restrict__ aw)
{
  int gc = blockIdx.x;
  int q = threadIdx.x;
  int g = gc / 3, c = gc - g * 3;
  float mv[3], lv[3];
  float M = -1e30f;
  #pragma unroll
  for (int s = 0; s < 3; s++) {
    const float* mlp = ml + ((size_t)s * 576 + gc) * 384;
    mv[s] = mlp[q];
    lv[s] = mlp[192 + q];
    M = fmaxf(M, mv[s]);
  }
  float L = 0.f, wgt[3];
  #pragma unroll
  for (int s = 0; s < 3; s++) { wgt[s] = lv[s] * __expf(mv[s] - M); L += wgt[s]; }
  float invL = 1.f / L;
  #pragma unroll
  for (int s = 0; s < 3; s++) wgt[s] *= invL;
  f16 row[64];
  #pragma unroll
  for (int d = 0; d < 64; d++) {
    float a = 0.f;
    #pragma unroll
    for (int s = 0; s < 3; s++)
      a += wgt[s] * (float)parth[((size_t)s * 576 + gc) * 12288 + d * 192 + q];
    row[d] = (f16)a;
  }
  f16* ap = aw + (size_t)g * 36864 + (size_t)(c * 192 + q) * 64;
  #pragma unroll
  for (int j = 0; j < 8; j++) *(v8hf*)(ap + j * 8) = *(v8hf*)(row + j * 8);
}

// ------------------------------------------------------------------
extern "C" void kernel_launch(void* const* d_in, const int* in_sizes, int n_in,
                              void* d_out, int out_size, void* d_ws, size_t ws_size,
                              hipStream_t stream) {
  const float* x    = (const float*)d_in[0];
  const float* dist = (const float*)d_in[1];
  const float* lg   = (const float*)d_in[2];
  const float* lb   = (const float*)d_in[3];
  const float* Wq   = (const float*)d_in[4];
  const float* bq   = (const float*)d_in[5];
  const float* Wk   = (const float*)d_in[6];
  const float* bk   = (const float*)d_in[7];
  const float* Wv   = (const float*)d_in[8];
  const float* bv   = (const float*)d_in[9];
  const float* Wo   = (const float*)d_in[10];
  const float* bo   = (const float*)d_in[11];
  const float* ak   = (const float*)d_in[12];
  const float* av   = (const float*)d_in[13];

  f16* ws = (f16*)d_ws;
  f16* xn = ws;                 // later reused as vt
  f16* qw = ws + SZH;
  f16* kw = ws + 2 * SZH;
  f16* vw = ws + 3 * SZH;       // later reused as aw
  f16* wt = ws + 4 * SZH;       // 4 x 768*768 f16
  float* fbase   = (float*)(wt + 4 * 589824);
  float* biasqkv = fbase;                       // 2304
  float* rates   = fbase + 2304;                // 128
  f16* parth     = (f16*)(fbase + 2432);        // 3*576*12288 f16
  float* mlb     = (float*)(parth + (size_t)3 * 576 * 12288);  // 3*576*384 f32
  f16* vtb = xn;
  f16* aw  = vw;

  size_t need_split = ((size_t)4 * SZH + 4 * 589824 + (size_t)3 * 576 * 12288) * 2
                    + ((size_t)2432 + (size_t)3 * 576 * 384) * 4;
  int ns = (ws_size >= need_split) ? 3 : 1;

  prep_kernel<<<9216 + 576 + 1, 256, 0, stream>>>(x, lg, lb, Wq, Wk, Wv, Wo, ak, av,
                                                  bq, bk, bv, xn, wt, biasqkv, rates);
  gemm_kernel<<<dim3(72, 18), 256, 0, stream>>>(xn, wt, biasqkv, qw, nullptr, 0);
  vt_kernel<<<dim3(192, 9), 256, 0, stream>>>(vw, vtb);
  attn_kernel<<<dim3(576, ns), 384, 0, stream>>>(qw, kw, vtb, dist, rates, aw, parth, mlb, ns);
  if (ns > 1)
    comb_kernel<<<576, 192, 0, stream>>>(parth, mlb, aw);
  gemm_kernel<<<dim3(72, 6), 256, 0, stream>>>(aw, wt + 3 * 589824, bo, nullptr, (float*)d_out, 1);
}

// Round 12
// 166.930 us; speedup vs baseline: 1.0347x; 1.0347x over previous
//
#include <hip/hip_runtime.h>
#include <hip/hip_fp16.h>

typedef _Float16 f16;
typedef _Float16 v2hf __attribute__((ext_vector_type(2)));
typedef _Float16 v8hf __attribute__((ext_vector_type(8)));
typedef __fp16 v2fp __attribute__((ext_vector_type(2)));
typedef float v4f __attribute__((ext_vector_type(4)));
typedef float v16f __attribute__((ext_vector_type(16)));
typedef unsigned int v4u __attribute__((ext_vector_type(4)));

#define NROW 9216
#define SZH ((size_t)NROW * 768)

__device__ __forceinline__ float softplus_f(float a) {
  return fmaxf(a, 0.f) + log1pf(__expf(-fabsf(a)));
}

__device__ __forceinline__ unsigned int packh(float a, float b) {
  union { v2fp h; unsigned int u; } z;
  z.h = __builtin_amdgcn_cvt_pkrtz(a, b);
  return z.u;
}

// async global->LDS, 16B per lane. LDS dest must be wave-uniform base; HW
// writes base + lane*16. Global addr is per-lane (pre-swizzled source).
__device__ __forceinline__ void gload16(const void* g, void* l) {
  __builtin_amdgcn_global_load_lds(
      (const __attribute__((address_space(1))) unsigned int*)(unsigned long long)g,
      (__attribute__((address_space(3))) unsigned int*)(unsigned int)(unsigned long long)l,
      16, 0, 0);
}

// ------------------------------------------------------------------
// prep: LayerNorm->f16 xn | W transpose->f16 | softplus rates + bias concat
// ------------------------------------------------------------------
__global__ __launch_bounds__(256) void prep_kernel(
    const float* __restrict__ x, const float* __restrict__ lg, const float* __restrict__ lb,
    const float* __restrict__ Wq, const float* __restrict__ Wk, const float* __restrict__ Wv,
    const float* __restrict__ Wo, const float* __restrict__ ak, const float* __restrict__ av,
    const float* __restrict__ bq, const float* __restrict__ bk, const float* __restrict__ bv,
    f16* __restrict__ xn, f16* __restrict__ wt, float* __restrict__ biasqkv,
    float* __restrict__ rates)
{
  __shared__ float tile[64][65];
  __shared__ float red[8];
  int bid = blockIdx.x, tid = threadIdx.x;
  if (bid < NROW) {
    const float* xr = x + (size_t)bid * 768;
    float v0 = xr[tid], v1 = xr[tid + 256], v2 = xr[tid + 512];
    float s1 = v0 + v1 + v2;
    float s2 = v0 * v0 + v1 * v1 + v2 * v2;
    #pragma unroll
    for (int off = 32; off >= 1; off >>= 1) {
      s1 += __shfl_xor(s1, off);
      s2 += __shfl_xor(s2, off);
    }
    int w = tid >> 6;
    if ((tid & 63) == 0) { red[w] = s1; red[4 + w] = s2; }
    __syncthreads();
    s1 = red[0] + red[1] + red[2] + red[3];
    s2 = red[4] + red[5] + red[6] + red[7];
    float mu = s1 * (1.f / 768.f);
    float var = s2 * (1.f / 768.f) - mu * mu;
    float rs = rsqrtf(var + 1e-5f);
    f16* xo = xn + (size_t)bid * 768;
    xo[tid]       = (f16)((v0 - mu) * rs * lg[tid] + lb[tid]);
    xo[tid + 256] = (f16)((v1 - mu) * rs * lg[tid + 256] + lb[tid + 256]);
    xo[tid + 512] = (f16)((v2 - mu) * rs * lg[tid + 512] + lb[tid + 512]);
    return;
  }
  bid -= NROW;
  if (bid < 576) {
    int wsel = bid / 144, t2 = bid % 144, tr = t2 / 12, tc = t2 % 12;
    const float* W = (wsel == 0) ? Wq : ((wsel == 1) ? Wk : ((wsel == 2) ? Wv : Wo));
    f16* WT = wt + (size_t)wsel * 589824;
    int r = tid >> 2, c0 = (tid & 3) * 16;
    #pragma unroll
    for (int j = 0; j < 16; j++)
      tile[r][c0 + j] = W[(size_t)(tr * 64 + r) * 768 + tc * 64 + c0 + j];
    __syncthreads();
    #pragma unroll
    for (int j = 0; j < 16; j++)
      WT[(size_t)(tc * 64 + r) * 768 + tr * 64 + c0 + j] = (f16)tile[c0 + j][r];
    return;
  }
  if (tid < 64) rates[tid] = softplus_f(ak[tid]);
  else if (tid < 128) rates[tid] = softplus_f(av[tid - 64]);
  for (int i = tid; i < 2304; i += 256)
    biasqkv[i] = (i < 768) ? bq[i] : ((i < 1536) ? bk[i - 768] : bv[i - 1536]);
}

// ------------------------------------------------------------------
// GEMM: A[M,768](f16) x WT[N,768](f16 pre-transposed) + bias[N]
// 128x128 tile, 256 thr, K-step 64, DOUBLE-BUFFERED global_load_lds(16B)
// with counted vmcnt(8) (T4): tile t+1's loads overlap tile t's compute;
// never drain to 0 in the loop. Raw s_barrier (no implicit vmcnt(0)).
// XCD-chunked block swizzle (nwg % 8 == 0 for both grids).
// ------------------------------------------------------------------
__global__ __launch_bounds__(256) void gemm_kernel(
    const f16* __restrict__ A, const f16* __restrict__ WT,
    const float* __restrict__ bias,
    f16* __restrict__ outh, float* __restrict__ outf, int f32out)
{
  __shared__ __align__(16) f16 At[2][128 * 64];
  __shared__ __align__(16) f16 Bt[2][128 * 64];
  int bid0 = blockIdx.y * gridDim.x + blockIdx.x;
  int nwg = gridDim.x * gridDim.y;
  int nid = (bid0 & 7) * (nwg >> 3) + (bid0 >> 3);
  int cols = gridDim.y;
  int mb = nid / cols, nb = nid % cols;
  int tid = threadIdx.x, lane = tid & 63, w = tid >> 6;
  int wr = w >> 1, wc = w & 1;
  v4f acc[4][4];
  #pragma unroll
  for (int i = 0; i < 4; i++)
    #pragma unroll
    for (int j = 0; j < 4; j++) acc[i][j] = (v4f){0.f, 0.f, 0.f, 0.f};
  int arow0 = mb * 128, brow0 = nb * 128;
  int rb = w * 32 + (lane >> 3);      // tile row this lane stages (j*8 step)
  int ch = lane & 7;                  // 16B chunk within 128B row
  // stage one 128x64 K-tile pair into buffer half `buf` (8 vmem instr/wave)
  auto stage = [&](int buf, int k0) {
    #pragma unroll
    for (int j = 0; j < 4; j++) {
      int row = rb + j * 8;
      int sc = ((ch ^ (row & 7)) << 3);
      gload16(A  + (size_t)(arow0 + row) * 768 + k0 + sc, (char*)At[buf] + w * 4096 + j * 1024);
      gload16(WT + (size_t)(brow0 + row) * 768 + k0 + sc, (char*)Bt[buf] + w * 4096 + j * 1024);
    }
  };
  stage(0, 0);
  for (int ks = 0; ks < 12; ++ks) {
    int cur = ks & 1;
    if (ks < 11) {
      stage(cur ^ 1, (ks + 1) * 64);
      asm volatile("s_waitcnt vmcnt(8)" ::: "memory");   // current tile landed
    } else {
      asm volatile("s_waitcnt vmcnt(0)" ::: "memory");
    }
    __builtin_amdgcn_s_barrier();
    __builtin_amdgcn_sched_barrier(0);
    v8hf bf[4][2];
    #pragma unroll
    for (int cf = 0; cf < 4; cf++)
      #pragma unroll
      for (int kk = 0; kk < 2; kk++) {
        int row = wc * 64 + cf * 16 + (lane & 15);
        int bc = kk * 64 + ((lane >> 4) << 4);
        bf[cf][kk] = *(const v8hf*)((char*)Bt[cur] + row * 128 + (bc ^ ((row & 7) << 4)));
      }
    #pragma unroll
    for (int rf = 0; rf < 4; rf++) {
      v8hf af[2];
      int row = wr * 64 + rf * 16 + (lane & 15);
      #pragma unroll
      for (int kk = 0; kk < 2; kk++) {
        int bc = kk * 64 + ((lane >> 4) << 4);
        af[kk] = *(const v8hf*)((char*)At[cur] + row * 128 + (bc ^ ((row & 7) << 4)));
      }
      #pragma unroll
      for (int cf = 0; cf < 4; cf++) {
        acc[rf][cf] = __builtin_amdgcn_mfma_f32_16x16x32_f16(af[0], bf[cf][0], acc[rf][cf], 0, 0, 0);
        acc[rf][cf] = __builtin_amdgcn_mfma_f32_16x16x32_f16(af[1], bf[cf][1], acc[rf][cf], 0, 0, 0);
      }
    }
    __builtin_amdgcn_sched_barrier(0);
    __builtin_amdgcn_s_barrier();   // all waves done reading buf[cur] (restaged next iter)
  }
  #pragma unroll
  for (int cf = 0; cf < 4; cf++) {
    int col = nb * 128 + wc * 64 + cf * 16 + (lane & 15);
    float bb = bias[col];
    int z = col / 768;
    int colz = col - z * 768;
    #pragma unroll
    for (int rf = 0; rf < 4; rf++) {
      int row0 = mb * 128 + wr * 64 + rf * 16 + ((lane >> 4) << 2);
      #pragma unroll
      for (int r = 0; r < 4; r++) {
        float val = acc[rf][cf][r] + bb;
        if (f32out) outf[(size_t)(row0 + r) * 768 + col] = val;
        else outh[(size_t)z * SZH + (size_t)(row0 + r) * 768 + colz] = (f16)val;
      }
    }
  }
}

// ------------------------------------------------------------------
// vt: per-head transpose vw [g][576][64] -> vt [g][64][576]
// ------------------------------------------------------------------
__global__ __launch_bounds__(256) void vt_kernel(const f16* __restrict__ vw, f16* __restrict__ vt)
{
  __shared__ f16 tile[64][72];
  int g = blockIdx.x, tc = blockIdx.y;
  int tid = threadIdx.x;
  int tr = tid >> 2, c16 = (tid & 3) * 16;
  const f16* src = vw + (size_t)g * 36864 + (size_t)(tc * 64 + tr) * 64 + c16;
  *(v8hf*)&tile[tr][c16] = *(const v8hf*)src;
  *(v8hf*)&tile[tr][c16 + 8] = *(const v8hf*)(src + 8);
  __syncthreads();
  int d = tid >> 2, t16 = (tid & 3) * 16;
  f16 outv[16];
  #pragma unroll
  for (int j = 0; j < 16; j++) outv[j] = tile[t16 + j][d];
  f16* dst = vt + (size_t)g * 36864 + (size_t)d * 576 + tc * 64 + t16;
  *(v8hf*)dst = *(v8hf*)outv;
  *(v8hf*)(dst + 8) = *(v8hf*)(outv + 8);
}

// ------------------------------------------------------------------
// Attention: block = (gc in [0,576) XCD-swizzled, slice). 6 waves x 32 q.
// Swapped QK^T (S^T via mfma_32x32x16), in-register softmax + P exchange,
// defer-max (T13, THR=8). nslice==3: f16 normalized partials + (m,l).
// ------------------------------------------------------------------
__global__ __launch_bounds__(384, 3) void attn_kernel(
    const f16* __restrict__ qw, const f16* __restrict__ kw, const f16* __restrict__ vt,
    const float* __restrict__ dist, const float* __restrict__ rates,
    f16* __restrict__ aw, f16* __restrict__ parth, float* __restrict__ ml, int nslice)
{
  __shared__ __align__(16) f16 Ke[64 * 64];
  __shared__ __align__(16) f16 Vt[64 * 64];
  __shared__ float dl[576];
  __shared__ float rkv[128];
  int gc = (blockIdx.x & 7) * 72 + (blockIdx.x >> 3);  // bijective (576 = 8*72)
  int sl = blockIdx.y;
  int g = gc / 3, c = gc - g * 3;
  int tid = threadIdx.x, lane = tid & 63, w = tid >> 6;
  int l31 = lane & 31, h = lane >> 5;
  int ntile = 9 / nslice;
  size_t hbase = (size_t)g * 36864;
  if (tid < 128) rkv[tid] = rates[tid];
  for (int t = tid; t < ntile * 64; t += 384)
    dl[t] = dist[(size_t)gc * 576 + sl * ntile * 64 + t];
  __syncthreads();
  v8hf qf[4];
  {
    const f16* qp = qw + hbase + (size_t)(c * 192 + w * 32 + l31) * 64 + h * 8;
    #pragma unroll
    for (int kk = 0; kk < 4; kk++) {
      v8hf v = *(const v8hf*)(qp + kk * 16);
      #pragma unroll
      for (int j = 0; j < 8; j++) v[j] = v[j] * (f16)0.125f;
      qf[kk] = v;
    }
  }
  v16f o0, o1;
  #pragma unroll
  for (int i = 0; i < 16; i++) { o0[i] = 0.f; o1[i] = 0.f; }
  float mrun = -1e30f, lrun = 0.f;
  for (int t = 0; t < ntile; ++t) {
    int mbase = sl * ntile * 64 + t * 64;
    int mloc = t * 64;
    for (int u = tid; u < 1024; u += 384) {
      if (u < 512) {
        int mm = u >> 3, d8 = (u & 7) * 8;
        float dv = dl[mloc + mm];
        v8hf kv = *(const v8hf*)(kw + hbase + (size_t)(mbase + mm) * 64 + d8);
        #pragma unroll
        for (int j = 0; j < 8; j++)
          kv[j] = (f16)((float)kv[j] + __expf(-rkv[d8 + j] * dv));
        *(v8hf*)((char*)Ke + mm * 128 + ((d8 * 2) ^ ((mm & 7) << 4))) = kv;
      } else {
        int uu = u - 512;
        int dd = uu >> 3, m8 = (uu & 7) * 8;
        float rv = rkv[64 + dd];
        v8hf vv = *(const v8hf*)(vt + hbase + (size_t)dd * 576 + mbase + m8);
        #pragma unroll
        for (int j = 0; j < 8; j++)
          vv[j] = (f16)((float)vv[j] + __expf(-rv * dl[mloc + m8 + j]));
        *(v8hf*)((char*)Vt + dd * 128 + ((m8 * 2) ^ ((dd & 7) << 4))) = vv;
      }
    }
    __syncthreads();
    v16f s0, s1;
    #pragma unroll
    for (int i = 0; i < 16; i++) { s0[i] = 0.f; s1[i] = 0.f; }
    #pragma unroll
    for (int kk = 0; kk < 4; kk++) {
      int bc = kk * 32 + h * 16;
      int sw0 = (l31 & 7) << 4;
      v8hf a0 = *(const v8hf*)((char*)Ke + l31 * 128 + (bc ^ sw0));
      v8hf a1 = *(const v8hf*)((char*)Ke + (32 + l31) * 128 + (bc ^ sw0));
      s0 = __builtin_amdgcn_mfma_f32_32x32x16_f16(a0, qf[kk], s0, 0, 0, 0);
      s1 = __builtin_amdgcn_mfma_f32_32x32x16_f16(a1, qf[kk], s1, 0, 0, 0);
    }
    float tmax = s0[0];
    #pragma unroll
    for (int i = 1; i < 16; i++) tmax = fmaxf(tmax, s0[i]);
    #pragma unroll
    for (int i = 0; i < 16; i++) tmax = fmaxf(tmax, s1[i]);
    tmax = fmaxf(tmax, __shfl_xor(tmax, 32));
    // T13 defer-max: skip O-rescale when per-tile growth <= 8 (P <= e^8, f16-safe)
    if (!__all(tmax - mrun <= 8.f)) {
      float mnew = fmaxf(mrun, tmax);
      float alpha = __expf(mrun - mnew);
      lrun *= alpha;
      #pragma unroll
      for (int i = 0; i < 16; i++) { o0[i] *= alpha; o1[i] *= alpha; }
      mrun = mnew;
    }
    float rs = 0.f;
    #pragma unroll
    for (int i = 0; i < 16; i++) { float p = __expf(s0[i] - mrun); s0[i] = p; rs += p; }
    #pragma unroll
    for (int i = 0; i < 16; i++) { float p = __expf(s1[i] - mrun); s1[i] = p; rs += p; }
    rs += __shfl_xor(rs, 32);
    lrun += rs;
    unsigned int Wd[16], Xd[16];
    #pragma unroll
    for (int i = 0; i < 8; i++) {
      Wd[i]     = packh(s0[2 * i], s0[2 * i + 1]);
      Wd[8 + i] = packh(s1[2 * i], s1[2 * i + 1]);
    }
    #pragma unroll
    for (int i = 0; i < 16; i++) Xd[i] = __shfl_xor((int)Wd[i], 32);
    v4u fw[4];
    fw[0] = h ? (v4u){Xd[2],  Xd[3],  Wd[2],  Wd[3]}  : (v4u){Wd[0],  Wd[1],  Xd[0],  Xd[1]};
    fw[1] = h ? (v4u){Xd[6],  Xd[7],  Wd[6],  Wd[7]}  : (v4u){Wd[4],  Wd[5],  Xd[4],  Xd[5]};
    fw[2] = h ? (v4u){Xd[10], Xd[11], Wd[10], Wd[11]} : (v4u){Wd[8],  Wd[9],  Xd[8],  Xd[9]};
    fw[3] = h ? (v4u){Xd[14], Xd[15], Wd[14], Wd[15]} : (v4u){Wd[12], Wd[13], Xd[12], Xd[13]};
    #pragma unroll
    for (int kk = 0; kk < 4; kk++) {
      int bc = kk * 32 + h * 16;
      int sw0 = (l31 & 7) << 4;
      v8hf a0 = *(const v8hf*)((char*)Vt + l31 * 128 + (bc ^ sw0));
      v8hf a1 = *(const v8hf*)((char*)Vt + (32 + l31) * 128 + (bc ^ sw0));
      union { v4u u; v8hf hh; } pb;
      pb.u = fw[kk];
      o0 = __builtin_amdgcn_mfma_f32_32x32x16_f16(a0, pb.hh, o0, 0, 0, 0);
      o1 = __builtin_amdgcn_mfma_f32_32x32x16_f16(a1, pb.hh, o1, 0, 0, 0);
    }
    __syncthreads();
  }
  float inv = 1.f / lrun;
  if (nslice == 1) {
    f16* ap = aw + hbase + (size_t)(c * 192 + w * 32 + l31) * 64;
    #pragma unroll
    for (int r = 0; r < 16; r++) {
      int d = (r & 3) + 8 * (r >> 2) + 4 * h;
      ap[d]      = (f16)(o0[r] * inv);
      ap[d + 32] = (f16)(o1[r] * inv);
    }
  } else {
    // normalized f16 partials (|O/l| <= max|V_eff|): halves split-K traffic
    f16* pp = parth + ((size_t)sl * 576 + gc) * 12288;
    int q = w * 32 + l31;
    #pragma unroll
    for (int r = 0; r < 16; r++) {
      int d = (r & 3) + 8 * (r >> 2) + 4 * h;
      pp[d * 192 + q]        = (f16)(o0[r] * inv);
      pp[(d + 32) * 192 + q] = (f16)(o1[r] * inv);
    }
    if (h == 0) {
      float* mlp = ml + ((size_t)sl * 576 + gc) * 384;
      mlp[q]       = mrun;
      mlp[192 + q] = lrun;
    }
  }
}

// ------------------------------------------------------------------
// combine split-K normalized partials -> aw f16
// O = sum_s (l_s e^{m_s-M} / L) * O_s_norm,  L = sum_s l_s e^{m_s-M}
// ------------------------------------------------------------------
__global__ __launch_bounds__(192) void comb_kernel(
    const f16* __restrict__ parth, const float* __restrict__ ml, f16* __restrict__ aw)
{
  int gc = blockIdx.x;
  int q = threadIdx.x;
  int g = gc / 3, c = gc - g * 3;
  float mv[3], lv[3];
  float M = -1e30f;
  #pragma unroll
  for (int s = 0; s < 3; s++) {
    const float* mlp = ml + ((size_t)s * 576 + gc) * 384;
    mv[s] = mlp[q];
    lv[s] = mlp[192 + q];
    M = fmaxf(M, mv[s]);
  }
  float L = 0.f, wgt[3];
  #pragma unroll
  for (int s = 0; s < 3; s++) { wgt[s] = lv[s] * __expf(mv[s] - M); L += wgt[s]; }
  float invL = 1.f / L;
  #pragma unroll
  for (int s = 0; s < 3; s++) wgt[s] *= invL;
  f16 row[64];
  #pragma unroll
  for (int d = 0; d < 64; d++) {
    float a = 0.f;
    #pragma unroll
    for (int s = 0; s < 3; s++)
      a += wgt[s] * (float)parth[((size_t)s * 576 + gc) * 12288 + d * 192 + q];
    row[d] = (f16)a;
  }
  f16* ap = aw + (size_t)g * 36864 + (size_t)(c * 192 + q) * 64;
  #pragma unroll
  for (int j = 0; j < 8; j++) *(v8hf*)(ap + j * 8) = *(v8hf*)(row + j * 8);
}

// ------------------------------------------------------------------
extern "C" void kernel_launch(void* const* d_in, const int* in_sizes, int n_in,
                              void* d_out, int out_size, void* d_ws, size_t ws_size,
                              hipStream_t stream) {
  const float* x    = (const float*)d_in[0];
  const float* dist = (const float*)d_in[1];
  const float* lg   = (const float*)d_in[2];
  const float* lb   = (const float*)d_in[3];
  const float* Wq   = (const float*)d_in[4];
  const float* bq   = (const float*)d_in[5];
  const float* Wk   = (const float*)d_in[6];
  const float* bk   = (const float*)d_in[7];
  const float* Wv   = (const float*)d_in[8];
  const float* bv   = (const float*)d_in[9];
  const float* Wo   = (const float*)d_in[10];
  const float* bo   = (const float*)d_in[11];
  const float* ak   = (const float*)d_in[12];
  const float* av   = (const float*)d_in[13];

  f16* ws = (f16*)d_ws;
  f16* xn = ws;                 // later reused as vt
  f16* qw = ws + SZH;
  f16* kw = ws + 2 * SZH;
  f16* vw = ws + 3 * SZH;       // later reused as aw
  f16* wt = ws + 4 * SZH;       // 4 x 768*768 f16
  float* fbase   = (float*)(wt + 4 * 589824);
  float* biasqkv = fbase;                       // 2304
  float* rates   = fbase + 2304;                // 128
  f16* parth     = (f16*)(fbase + 2432);        // 3*576*12288 f16
  float* mlb     = (float*)(parth + (size_t)3 * 576 * 12288);  // 3*576*384 f32
  f16* vtb = xn;
  f16* aw  = vw;

  size_t need_split = ((size_t)4 * SZH + 4 * 589824 + (size_t)3 * 576 * 12288) * 2
                    + ((size_t)2432 + (size_t)3 * 576 * 384) * 4;
  int ns = (ws_size >= need_split) ? 3 : 1;

  prep_kernel<<<9216 + 576 + 1, 256, 0, stream>>>(x, lg, lb, Wq, Wk, Wv, Wo, ak, av,
                                                  bq, bk, bv, xn, wt, biasqkv, rates);
  gemm_kernel<<<dim3(72, 18), 256, 0, stream>>>(xn, wt, biasqkv, qw, nullptr, 0);
  vt_kernel<<<dim3(192, 9), 256, 0, stream>>>(vw, vtb);
  attn_kernel<<<dim3(576, ns), 384, 0, stream>>>(qw, kw, vtb, dist, rates, aw, parth, mlb, ns);
  if (ns > 1)
    comb_kernel<<<576, 192, 0, stream>>>(parth, mlb, aw);
  gemm_kernel<<<dim3(72, 6), 256, 0, stream>>>(aw, wt + 3 * 589824, bo, nullptr, (float*)d_out, 1);
}